// Round 1
// baseline (330.867 us; speedup 1.0000x reference)
//
#include <hip/hip_runtime.h>
#include <hip/hip_bf16.h>
#include <stdint.h>

// Problem: B=256 rows, D=2048, I=5504, k_sel=128, T=1.
// T=1 => softmax over size-1 axis == 1 => attention output == V. q/k/RoPE dead.
// Pipeline: router scores -> top-128 -> per-row: rms1 -> V=h@wv+bv -> o=V@wo,
// x1=x+o -> rms2 -> G=h2@Wg, U=h2@Wu -> M=silu(G)*U -> out[sel]=x1+M@Wd.
// All GEMMs: M=128 (full in one block tile), bf16 MFMA 16x16x32, weights
// converted fp32->bf16 inline during LDS staging, split-K with fp32 atomics.

#define D_ 2048
#define I_ 5504
#define NROWS 256
#define KSEL 128

typedef __attribute__((ext_vector_type(8))) short short8;   // 8 x bf16
typedef __attribute__((ext_vector_type(4))) float floatx4;  // MFMA acc

__device__ __forceinline__ unsigned short f2bf(float f) {
  union { float f; unsigned int u; } v; v.f = f;
  unsigned int r = (v.u + 0x7FFFu + ((v.u >> 16) & 1u)) >> 16;  // RNE
  return (unsigned short)r;
}

// ---------------- K1: router scores ----------------
__global__ void k_router(const float* __restrict__ hid, const float* __restrict__ rw,
                         const float* __restrict__ rb, float* __restrict__ scores) {
  int b = blockIdx.x, t = threadIdx.x;
  const float* x = hid + (size_t)b * D_;
  float s = 0.f;
  for (int i = t; i < D_; i += 256) s += x[i] * rw[i];
  for (int o = 32; o; o >>= 1) s += __shfl_down(s, o);
  __shared__ float red[4];
  if ((t & 63) == 0) red[t >> 6] = s;
  __syncthreads();
  if (t == 0) scores[b] = red[0] + red[1] + red[2] + red[3] + rb[0];
}

// ---------------- K2: exact top-k (rank with index tie-break) ----------------
__global__ void k_select(const float* __restrict__ scores, const int* __restrict__ kptr,
                         int* __restrict__ sel) {
  __shared__ float sv[NROWS];
  __shared__ int cnt;
  int t = threadIdx.x;
  sv[t] = scores[t];
  if (t == 0) cnt = 0;
  __syncthreads();
  float s = sv[t];
  int c = 0;
  for (int j = 0; j < NROWS; ++j) {
    float o = sv[j];
    c += (o > s) || (o == s && j < t);
  }
  if (c < *kptr) {            // expects k_sel == 128 (grids below are sized for it)
    int pos = atomicAdd(&cnt, 1);
    sel[pos] = t;             // order within sel is irrelevant (set semantics)
  }
}

// ---------------- K3: out = hidden ----------------
__global__ void k_copy(const float4* __restrict__ src, float4* __restrict__ dst, int n4) {
  int i = blockIdx.x * blockDim.x + threadIdx.x;
  if (i < n4) dst[i] = src[i];
}

// ---------------- K4: rms1, init V=bv, X1=x, H bf16 ----------------
__global__ void k_rms1(const float* __restrict__ hid, const int* __restrict__ sel,
                       const float* __restrict__ ln1, const float* __restrict__ bv,
                       unsigned short* __restrict__ Hb, float* __restrict__ V,
                       float* __restrict__ X1) {
  int i = blockIdx.x, t = threadIdx.x;
  int r = sel[i];
  const float* x = hid + (size_t)r * D_;
  float xs[8]; float ss = 0.f;
#pragma unroll
  for (int c = 0; c < 8; ++c) { float v = x[t + c * 256]; xs[c] = v; ss += v * v; }
  for (int o = 32; o; o >>= 1) ss += __shfl_down(ss, o);
  __shared__ float red[4];
  if ((t & 63) == 0) red[t >> 6] = ss;
  __syncthreads();
  float inv = rsqrtf((red[0] + red[1] + red[2] + red[3]) * (1.0f / D_) + 1e-6f);
#pragma unroll
  for (int c = 0; c < 8; ++c) {
    int idx = t + c * 256;
    size_t o_ = (size_t)i * D_ + idx;
    Hb[o_] = f2bf(xs[c] * inv * ln1[idx]);
    V[o_] = bv[idx];
    X1[o_] = xs[c];
  }
}

// ---------------- K5b: fp32 -> bf16 ----------------
__global__ void k_cvt(const float* __restrict__ src, unsigned short* __restrict__ dst, int n) {
  int i = blockIdx.x * 256 + threadIdx.x;
  if (i < n) dst[i] = f2bf(src[i]);
}

// ---------------- K7: rms2, zero G/U ----------------
__global__ void k_rms2(const float* __restrict__ X1, const float* __restrict__ ln2,
                       unsigned short* __restrict__ H2b, float* __restrict__ G,
                       float* __restrict__ U) {
  int i = blockIdx.x, t = threadIdx.x;
  const float* x = X1 + (size_t)i * D_;
  float xs[8]; float ss = 0.f;
#pragma unroll
  for (int c = 0; c < 8; ++c) { float v = x[t + c * 256]; xs[c] = v; ss += v * v; }
  for (int o = 32; o; o >>= 1) ss += __shfl_down(ss, o);
  __shared__ float red[4];
  if ((t & 63) == 0) red[t >> 6] = ss;
  __syncthreads();
  float inv = rsqrtf((red[0] + red[1] + red[2] + red[3]) * (1.0f / D_) + 1e-6f);
#pragma unroll
  for (int c = 0; c < 8; ++c) {
    int idx = t + c * 256;
    H2b[(size_t)i * D_ + idx] = f2bf(xs[c] * inv * ln2[idx]);
  }
  for (int j = t; j < I_; j += 256) {
    G[(size_t)i * I_ + j] = 0.f;
    U[(size_t)i * I_ + j] = 0.f;
  }
}

// ---------------- K9: M = silu(G)*U (bf16), out[sel] = X1 ----------------
__global__ void k_silu_scatter(const float* __restrict__ G, const float* __restrict__ U,
                               unsigned short* __restrict__ Mb,
                               const float* __restrict__ X1, const int* __restrict__ sel,
                               float* __restrict__ out) {
  int tid = blockIdx.x * 256 + threadIdx.x;
  int stride = gridDim.x * 256;
  const int nM = KSEL * I_;    // 704512
  for (int i = tid; i < nM; i += stride) {
    float g = G[i], u = U[i];
    float m = (g / (1.f + expf(-g))) * u;
    Mb[i] = f2bf(m);
  }
  const int nX = KSEL * D_;    // 262144
  for (int i = tid; i < nX; i += stride) {
    int row = i >> 11, col = i & 2047;
    out[(size_t)sel[row] * D_ + col] = X1[i];
  }
}

// ---------------- GEMM: C[128xN] (+)= A[128xK](bf16) @ B[KxN](fp32->bf16) ----------------
// 128x128 tile per block, BK=32, 4 waves (2x2), 16x16x32 bf16 MFMA, split-K atomics.
__global__ __launch_bounds__(256)
void k_gemm(const unsigned short* __restrict__ A, const float* __restrict__ B,
            float* __restrict__ C, const int* __restrict__ rowmap,
            int K, int N, int KT, int ldc) {
  const int bn = blockIdx.x;
  const int kt0 = blockIdx.y * KT;
  const int kt1 = min(K, kt0 + KT);
  const int tid = threadIdx.x;
  const int lane = tid & 63;
  const int wave = tid >> 6;
  const int wm = wave >> 1, wn = wave & 1;
  const int fm = lane & 15, kq = lane >> 4;

  __shared__ unsigned short Asm[128 * 40];  // [m][k], stride 40 (pad: 16B aligned, low conflict)
  __shared__ unsigned short Bsm[128 * 40];  // [n][k], stride 40

  floatx4 acc[4][4] = {};

  const int ar = tid >> 1;
  const int ac = (tid & 1) * 16;
  const int bnn = tid & 127;
  const int bkh = (tid >> 7) * 16;
  const unsigned short* Abase = A + (size_t)ar * K + ac;
  const float* Bbase = B + (size_t)bn * 128 + bnn;

  for (int kt = kt0; kt < kt1; kt += 32) {
    // global loads into regs
    const uint4* Ag = (const uint4*)(Abase + kt);
    uint4 a0 = Ag[0], a1 = Ag[1];
    float bvv[16];
    const float* Bg = Bbase + (size_t)(kt + bkh) * N;
#pragma unroll
    for (int r = 0; r < 16; ++r) bvv[r] = Bg[(size_t)r * N];  // coalesced across lanes
    __syncthreads();
    // LDS stores (convert B fp32->bf16 inline)
    uint4* Ad = (uint4*)&Asm[ar * 40 + ac];
    Ad[0] = a0; Ad[1] = a1;
    alignas(16) unsigned short us[16];
#pragma unroll
    for (int r = 0; r < 16; ++r) us[r] = f2bf(bvv[r]);
    uint4* Bd = (uint4*)&Bsm[bnn * 40 + bkh];
    Bd[0] = ((const uint4*)us)[0];
    Bd[1] = ((const uint4*)us)[1];
    __syncthreads();
    // fragments + MFMA
    short8 af[4], bfr[4];
#pragma unroll
    for (int i = 0; i < 4; ++i)
      af[i] = *(const short8*)&Asm[(wm * 64 + i * 16 + fm) * 40 + kq * 8];
#pragma unroll
    for (int j = 0; j < 4; ++j)
      bfr[j] = *(const short8*)&Bsm[(wn * 64 + j * 16 + fm) * 40 + kq * 8];
#pragma unroll
    for (int i = 0; i < 4; ++i)
#pragma unroll
      for (int j = 0; j < 4; ++j)
        acc[i][j] = __builtin_amdgcn_mfma_f32_16x16x32_bf16(af[i], bfr[j], acc[i][j], 0, 0, 0);
  }

  // epilogue: atomic accumulate (C/D layout: col=lane&15, row=(lane>>4)*4+reg)
#pragma unroll
  for (int i = 0; i < 4; ++i) {
#pragma unroll
    for (int r = 0; r < 4; ++r) {
      int row = wm * 64 + i * 16 + kq * 4 + r;
      size_t rbase = rowmap ? (size_t)rowmap[row] * ldc : (size_t)row * ldc;
#pragma unroll
      for (int j = 0; j < 4; ++j) {
        int col = bn * 128 + wn * 64 + j * 16 + fm;
        atomicAdd(&C[rbase + col], acc[i][j][r]);
      }
    }
  }
}

extern "C" void kernel_launch(void* const* d_in, const int* in_sizes, int n_in,
                              void* d_out, int out_size, void* d_ws, size_t ws_size,
                              hipStream_t stream) {
  const float* hid = (const float*)d_in[0];
  const float* rw  = (const float*)d_in[3];
  const float* rb  = (const float*)d_in[4];
  const float* ln1 = (const float*)d_in[5];
  const float* ln2 = (const float*)d_in[6];
  const float* wv  = (const float*)d_in[11];
  const float* bv  = (const float*)d_in[12];
  const float* wo  = (const float*)d_in[13];
  const float* wg  = (const float*)d_in[14];
  const float* wu  = (const float*)d_in[15];
  const float* wd  = (const float*)d_in[16];
  const int*   kp  = (const int*)d_in[17];
  float* out = (float*)d_out;

  char* ws = (char*)d_ws;
  float*          scores = (float*)(ws);                         // 1 KB
  int*            sel    = (int*)(ws + 1024);                    // 512 B
  unsigned short* Hb     = (unsigned short*)(ws + 4096);         // 512 KB
  float*          V      = (float*)(ws + 4096 + 524288);         // 1 MB
  unsigned short* Vb     = (unsigned short*)((char*)V + 1048576);// 512 KB
  float*          X1     = (float*)((char*)Vb + 524288);         // 1 MB
  unsigned short* H2b    = (unsigned short*)((char*)X1 + 1048576);// 512 KB
  float*          G      = (float*)((char*)H2b + 524288);        // 2.69 MB
  float*          U      = (float*)((char*)G + 2818048);         // 2.69 MB
  unsigned short* Mb     = (unsigned short*)((char*)U + 2818048);// 1.34 MB  (~10.7 MB total)

  k_router<<<256, 256, 0, stream>>>(hid, rw, rb, scores);
  k_select<<<1, 256, 0, stream>>>(scores, kp, sel);
  k_copy<<<512, 256, 0, stream>>>((const float4*)hid, (float4*)out, 131072);
  k_rms1<<<128, 256, 0, stream>>>(hid, sel, ln1, bv, Hb, V, X1);
  // V += H @ wv   (K=2048, N=2048, KT=128 -> 256 blocks)
  k_gemm<<<dim3(16, 16), 256, 0, stream>>>(Hb, wv, V, nullptr, 2048, 2048, 128, 2048);
  k_cvt<<<1024, 256, 0, stream>>>(V, Vb, 262144);
  // X1 += Vb @ wo
  k_gemm<<<dim3(16, 16), 256, 0, stream>>>(Vb, wo, X1, nullptr, 2048, 2048, 128, 2048);
  k_rms2<<<128, 256, 0, stream>>>(X1, ln2, H2b, G, U);
  // G += H2 @ w_gate ; U += H2 @ w_up   (N=5504, KT=256 -> 344 blocks each)
  k_gemm<<<dim3(43, 8), 256, 0, stream>>>(H2b, wg, G, nullptr, 2048, 5504, 256, 5504);
  k_gemm<<<dim3(43, 8), 256, 0, stream>>>(H2b, wu, U, nullptr, 2048, 5504, 256, 5504);
  k_silu_scatter<<<1024, 256, 0, stream>>>(G, U, Mb, X1, sel, out);
  // out[sel] += Mb @ w_down  (K=5504, KT=352 -> 256 blocks)
  k_gemm<<<dim3(16, 16), 256, 0, stream>>>(Mb, wd, out, sel, 5504, 2048, 352, 2048);
}

// Round 2
// 318.733 us; speedup vs baseline: 1.0381x; 1.0381x over previous
//
#include <hip/hip_runtime.h>
#include <hip/hip_bf16.h>
#include <stdint.h>

// T=1 => softmax over size-1 axis == 1 => attention output == V; q/k/RoPE dead.
// Pipeline: router -> top-128 (deterministic rank) -> rms1 -> V=h@wv+bv ->
// X1=x+V@wo -> rms2 -> G,U = h2@{Wg,Wu} (fused dual-B GEMM) -> Mb=silu(G)*U ->
// out = copy/scatter -> out[sel] += Mb@Wd.
// GEMMs: M=128, 128x64 tile, BK=32, bf16 MFMA 16x16x32, fp32 weights converted
// to bf16 inline during LDS staging, register-prefetch rotation to hide HBM
// latency behind MFMA, split-K with fp32 atomics.

#define D_ 2048
#define I_ 5504
#define NROWS 256
#define KSEL 128

typedef __attribute__((ext_vector_type(8))) short short8;   // 8 x bf16
typedef __attribute__((ext_vector_type(4))) float floatx4;  // MFMA acc

__device__ __forceinline__ unsigned short f2bf(float f) {
  union { float f; unsigned int u; } v; v.f = f;
  unsigned int r = (v.u + 0x7FFFu + ((v.u >> 16) & 1u)) >> 16;  // RNE
  return (unsigned short)r;
}

// ---------------- K1: router scores ----------------
__global__ void k_router(const float* __restrict__ hid, const float* __restrict__ rw,
                         const float* __restrict__ rb, float* __restrict__ scores) {
  int b = blockIdx.x, t = threadIdx.x;
  const float* x = hid + (size_t)b * D_;
  float s = 0.f;
  for (int i = t; i < D_; i += 256) s += x[i] * rw[i];
  for (int o = 32; o; o >>= 1) s += __shfl_down(s, o);
  __shared__ float red[4];
  if ((t & 63) == 0) red[t >> 6] = s;
  __syncthreads();
  if (t == 0) scores[b] = red[0] + red[1] + red[2] + red[3] + rb[0];
}

// ---------------- K2: exact top-k, deterministic (rank == slot) ----------------
__global__ void k_select(const float* __restrict__ scores, const int* __restrict__ kptr,
                         int* __restrict__ sel, int* __restrict__ pos) {
  __shared__ float sv[NROWS];
  int t = threadIdx.x;
  sv[t] = scores[t];
  __syncthreads();
  float s = sv[t];
  int c = 0;
  for (int j = 0; j < NROWS; ++j) {
    float o = sv[j];
    c += (o > s) || (o == s && j < t);
  }
  int k = *kptr;                 // k_sel == 128 (grids sized for it)
  if (c < k) sel[c] = t;
  pos[t] = (c < k) ? c : -1;
}

// ---------------- K3: rms1, init V=bv, X1=x, H bf16 ----------------
__global__ void k_rms1(const float* __restrict__ hid, const int* __restrict__ sel,
                       const float* __restrict__ ln1, const float* __restrict__ bv,
                       unsigned short* __restrict__ Hb, float* __restrict__ V,
                       float* __restrict__ X1) {
  int i = blockIdx.x, t = threadIdx.x;
  int r = sel[i];
  const float* x = hid + (size_t)r * D_;
  float xs[8]; float ss = 0.f;
#pragma unroll
  for (int c = 0; c < 8; ++c) { float v = x[t + c * 256]; xs[c] = v; ss += v * v; }
  for (int o = 32; o; o >>= 1) ss += __shfl_down(ss, o);
  __shared__ float red[4];
  if ((t & 63) == 0) red[t >> 6] = ss;
  __syncthreads();
  float inv = rsqrtf((red[0] + red[1] + red[2] + red[3]) * (1.0f / D_) + 1e-6f);
#pragma unroll
  for (int c = 0; c < 8; ++c) {
    int idx = t + c * 256;
    size_t o_ = (size_t)i * D_ + idx;
    Hb[o_] = f2bf(xs[c] * inv * ln1[idx]);
    V[o_] = bv[idx];
    X1[o_] = xs[c];
  }
}

// ---------------- K5: rms2, zero G/U ----------------
__global__ void k_rms2(const float* __restrict__ X1, const float* __restrict__ ln2,
                       unsigned short* __restrict__ H2b, float* __restrict__ G,
                       float* __restrict__ U) {
  int i = blockIdx.x, t = threadIdx.x;
  const float* x = X1 + (size_t)i * D_;
  float xs[8]; float ss = 0.f;
#pragma unroll
  for (int c = 0; c < 8; ++c) { float v = x[t + c * 256]; xs[c] = v; ss += v * v; }
  for (int o = 32; o; o >>= 1) ss += __shfl_down(ss, o);
  __shared__ float red[4];
  if ((t & 63) == 0) red[t >> 6] = ss;
  __syncthreads();
  float inv = rsqrtf((red[0] + red[1] + red[2] + red[3]) * (1.0f / D_) + 1e-6f);
#pragma unroll
  for (int c = 0; c < 8; ++c) {
    int idx = t + c * 256;
    H2b[(size_t)i * D_ + idx] = f2bf(xs[c] * inv * ln2[idx]);
  }
  for (int j = t; j < I_; j += 256) {
    G[(size_t)i * I_ + j] = 0.f;
    U[(size_t)i * I_ + j] = 0.f;
  }
}

// ---------------- K7: Mb = silu(G)*U ; out = copy/scatter ----------------
__global__ void k_silu_out(const float* __restrict__ G, const float* __restrict__ U,
                           unsigned short* __restrict__ Mb,
                           const float* __restrict__ X1, const int* __restrict__ pos,
                           const float* __restrict__ hid, float* __restrict__ out) {
  int tid = blockIdx.x * 256 + threadIdx.x;
  int stride = gridDim.x * 256;
  const int nM = KSEL * I_;    // 704512
  for (int i = tid; i < nM; i += stride) {
    float g = G[i], u = U[i];
    float m = (g / (1.f + expf(-g))) * u;
    Mb[i] = f2bf(m);
  }
  const int nO4 = NROWS * (D_ / 4);   // 131072 float4
  const float4* X14 = (const float4*)X1;
  const float4* H4 = (const float4*)hid;
  float4* O4 = (float4*)out;
  for (int i = tid; i < nO4; i += stride) {
    int row = i >> 9;             // 512 float4 per row
    int c4 = i & 511;
    int p = pos[row];
    O4[i] = (p >= 0) ? X14[(size_t)p * 512 + c4] : H4[i];
  }
}

// ---------------- GEMM: C[128xN] += A[128xK] @ B[KxN] ----------------
// 128x64 tile, BK=32, 4 waves (2x2: 64 rows x 32 cols each), 16x16x32 bf16 MFMA.
// Register-prefetch rotation: next tile's global loads issue during MFMA phase.
// AF32: A is fp32 (converted during staging). DUAL: second B/C pair (gate+up).
template<bool AF32, bool DUAL>
__global__ __launch_bounds__(256)
void k_gemm(const void* __restrict__ Ap, const float* __restrict__ B0,
            const float* __restrict__ B1, float* __restrict__ C0,
            float* __restrict__ C1, const int* __restrict__ rowmap,
            int K, int N, int KT, int ldc) {
  constexpr int SA = 40;  // LDS leading-dim pad (elems): 80 B rows, b128-aligned
  constexpr int SB = 40;
  const int bn = blockIdx.x;
  const int kt0 = blockIdx.y * KT;
  const int kt1 = min(K, kt0 + KT);
  const int tid = threadIdx.x;
  const int lane = tid & 63;
  const int wave = tid >> 6;
  const int wm = wave >> 1, wn = wave & 1;
  const int fm = lane & 15, kq = lane >> 4;

  __shared__ alignas(16) unsigned short Asm[128 * SA];
  __shared__ alignas(16) unsigned short Bsm0[64 * SB];
  __shared__ alignas(16) unsigned short Bsm1[DUAL ? 64 * SB : 8];

  floatx4 acc0[4][2] = {};
  floatx4 acc1[4][2] = {};

  // A staging map: thread -> (row ar, 16-elem col half ac)
  const int ar = tid >> 1;
  const int ac = (tid & 1) * 16;
  // B staging map: thread -> (2 cols n2, 4 rows from kh)
  const int n2 = (tid & 31) * 2;
  const int kh = (tid >> 5) * 4;

  const unsigned short* Ab = AF32 ? nullptr : (const unsigned short*)Ap + (size_t)ar * K + ac;
  const float*          Af = AF32 ? (const float*)Ap + (size_t)ar * K + ac : nullptr;
  const float* B0b = B0 + (size_t)bn * 64 + n2;
  const float* B1b = DUAL ? B1 + (size_t)bn * 64 + n2 : nullptr;

  // prefetch registers
  uint4 a16[2];            // bf16 A path
  float af32[16];          // fp32 A path
  float2 b0r[4], b1r[4];

  auto load_tile = [&](int kt) {
    if (AF32) {
#pragma unroll
      for (int r = 0; r < 4; ++r)
        *(float4*)&af32[r * 4] = *(const float4*)(Af + kt + r * 4);
    } else {
      const uint4* Ag = (const uint4*)(Ab + kt);
      a16[0] = Ag[0]; a16[1] = Ag[1];
    }
    const float* Bg0 = B0b + (size_t)(kt + kh) * N;
#pragma unroll
    for (int r = 0; r < 4; ++r) b0r[r] = *(const float2*)(Bg0 + (size_t)r * N);
    if (DUAL) {
      const float* Bg1 = B1b + (size_t)(kt + kh) * N;
#pragma unroll
      for (int r = 0; r < 4; ++r) b1r[r] = *(const float2*)(Bg1 + (size_t)r * N);
    }
  };

  load_tile(kt0);

  for (int kt = kt0; kt < kt1; kt += 32) {
    __syncthreads();   // previous iteration's LDS readers done
    // ---- store staged tile to LDS ----
    if (AF32) {
      alignas(16) unsigned short us[16];
#pragma unroll
      for (int r = 0; r < 16; ++r) us[r] = f2bf(af32[r]);
      uint4* Ad = (uint4*)&Asm[ar * SA + ac];
      Ad[0] = ((const uint4*)us)[0]; Ad[1] = ((const uint4*)us)[1];
    } else {
      uint4* Ad = (uint4*)&Asm[ar * SA + ac];
      Ad[0] = a16[0]; Ad[1] = a16[1];
    }
    {
      // transpose 4x2 fp32 -> two bf16x4 column segments
      unsigned long long w0 = (unsigned long long)f2bf(b0r[0].x)
                            | ((unsigned long long)f2bf(b0r[1].x) << 16)
                            | ((unsigned long long)f2bf(b0r[2].x) << 32)
                            | ((unsigned long long)f2bf(b0r[3].x) << 48);
      unsigned long long w1 = (unsigned long long)f2bf(b0r[0].y)
                            | ((unsigned long long)f2bf(b0r[1].y) << 16)
                            | ((unsigned long long)f2bf(b0r[2].y) << 32)
                            | ((unsigned long long)f2bf(b0r[3].y) << 48);
      *(unsigned long long*)&Bsm0[(n2 + 0) * SB + kh] = w0;
      *(unsigned long long*)&Bsm0[(n2 + 1) * SB + kh] = w1;
      if (DUAL) {
        unsigned long long v0 = (unsigned long long)f2bf(b1r[0].x)
                              | ((unsigned long long)f2bf(b1r[1].x) << 16)
                              | ((unsigned long long)f2bf(b1r[2].x) << 32)
                              | ((unsigned long long)f2bf(b1r[3].x) << 48);
        unsigned long long v1 = (unsigned long long)f2bf(b1r[0].y)
                              | ((unsigned long long)f2bf(b1r[1].y) << 16)
                              | ((unsigned long long)f2bf(b1r[2].y) << 32)
                              | ((unsigned long long)f2bf(b1r[3].y) << 48);
        *(unsigned long long*)&Bsm1[(n2 + 0) * SB + kh] = v0;
        *(unsigned long long*)&Bsm1[(n2 + 1) * SB + kh] = v1;
      }
    }
    __syncthreads();   // tile visible to all waves
    // ---- prefetch next tile (latency hides behind MFMA below) ----
    if (kt + 32 < kt1) load_tile(kt + 32);
    // ---- fragments + MFMA ----
    short8 afr[4], bf0[2], bf1[2];
#pragma unroll
    for (int i = 0; i < 4; ++i)
      afr[i] = *(const short8*)&Asm[(wm * 64 + i * 16 + fm) * SA + kq * 8];
#pragma unroll
    for (int j = 0; j < 2; ++j)
      bf0[j] = *(const short8*)&Bsm0[(wn * 32 + j * 16 + fm) * SB + kq * 8];
    if (DUAL) {
#pragma unroll
      for (int j = 0; j < 2; ++j)
        bf1[j] = *(const short8*)&Bsm1[(wn * 32 + j * 16 + fm) * SB + kq * 8];
    }
#pragma unroll
    for (int i = 0; i < 4; ++i) {
#pragma unroll
      for (int j = 0; j < 2; ++j) {
        acc0[i][j] = __builtin_amdgcn_mfma_f32_16x16x32_bf16(afr[i], bf0[j], acc0[i][j], 0, 0, 0);
        if (DUAL)
          acc1[i][j] = __builtin_amdgcn_mfma_f32_16x16x32_bf16(afr[i], bf1[j], acc1[i][j], 0, 0, 0);
      }
    }
  }

  // epilogue: atomic accumulate (C/D layout: col=lane&15, row=(lane>>4)*4+reg)
#pragma unroll
  for (int i = 0; i < 4; ++i) {
#pragma unroll
    for (int r = 0; r < 4; ++r) {
      int row = wm * 64 + i * 16 + kq * 4 + r;
      size_t rbase = rowmap ? (size_t)rowmap[row] * ldc : (size_t)row * ldc;
#pragma unroll
      for (int j = 0; j < 2; ++j) {
        int col = bn * 64 + wn * 32 + j * 16 + fm;
        atomicAdd(&C0[rbase + col], acc0[i][j][r]);
        if (DUAL) atomicAdd(&C1[rbase + col], acc1[i][j][r]);
      }
    }
  }
}

extern "C" void kernel_launch(void* const* d_in, const int* in_sizes, int n_in,
                              void* d_out, int out_size, void* d_ws, size_t ws_size,
                              hipStream_t stream) {
  const float* hid = (const float*)d_in[0];
  const float* rw  = (const float*)d_in[3];
  const float* rb  = (const float*)d_in[4];
  const float* ln1 = (const float*)d_in[5];
  const float* ln2 = (const float*)d_in[6];
  const float* wv  = (const float*)d_in[11];
  const float* bv  = (const float*)d_in[12];
  const float* wo  = (const float*)d_in[13];
  const float* wg  = (const float*)d_in[14];
  const float* wu  = (const float*)d_in[15];
  const float* wd  = (const float*)d_in[16];
  const int*   kp  = (const int*)d_in[17];
  float* out = (float*)d_out;

  char* ws = (char*)d_ws;
  float*          scores = (float*)(ws + 0);           // 1 KB
  int*            sel    = (int*)(ws + 1024);          // 512 B
  int*            pos    = (int*)(ws + 1536);          // 1 KB
  unsigned short* Hb     = (unsigned short*)(ws + 4096);        // 512 KB
  float*          V      = (float*)(ws + 528384);      // 1 MB
  float*          X1     = (float*)(ws + 1576960);     // 1 MB
  unsigned short* H2b    = (unsigned short*)(ws + 2625536);     // 512 KB
  float*          G      = (float*)(ws + 3149824);     // 2.69 MB
  float*          U      = (float*)(ws + 5967872);     // 2.69 MB
  unsigned short* Mb     = (unsigned short*)(ws + 8785920);     // 1.34 MB

  k_router<<<256, 256, 0, stream>>>(hid, rw, rb, scores);
  k_select<<<1, 256, 0, stream>>>(scores, kp, sel, pos);
  k_rms1<<<128, 256, 0, stream>>>(hid, sel, ln1, bv, Hb, V, X1);
  // V += H @ wv   (N=2048: 32 tiles x 8 splits, KT=256)
  k_gemm<false, false><<<dim3(32, 8), 256, 0, stream>>>(Hb, wv, nullptr, V, nullptr, nullptr, 2048, 2048, 256, 2048);
  // X1 += V @ wo  (A fp32, converted in staging)
  k_gemm<true, false><<<dim3(32, 8), 256, 0, stream>>>(V, wo, nullptr, X1, nullptr, nullptr, 2048, 2048, 256, 2048);
  k_rms2<<<128, 256, 0, stream>>>(X1, ln2, H2b, G, U);
  // G += H2 @ w_gate ; U += H2 @ w_up  (fused: 86 tiles x 4 splits, KT=512)
  k_gemm<false, true><<<dim3(86, 4), 256, 0, stream>>>(H2b, wg, wu, G, U, nullptr, 2048, 5504, 512, 5504);
  k_silu_out<<<1024, 256, 0, stream>>>(G, U, Mb, X1, pos, hid, out);
  // out[sel] += Mb @ w_down  (32 tiles x 8 splits, KT=704)
  k_gemm<false, false><<<dim3(32, 8), 256, 0, stream>>>(Mb, wd, nullptr, out, nullptr, sel, 5504, 2048, 704, 2048);
}

// Round 3
// 295.123 us; speedup vs baseline: 1.1211x; 1.0800x over previous
//
#include <hip/hip_runtime.h>
#include <hip/hip_bf16.h>
#include <stdint.h>

// T=1 => softmax over size-1 axis == 1 => attention output == V; q/k/RoPE dead.
// Pipeline: router -> top-128 -> rms1 -> V=h@wv+bv -> X1=x+V@wo -> rms2 ->
// G,U = h2@{Wg,Wu} (fused dual-B GEMM) -> Mb=silu(G)*U -> out copy/scatter ->
// out[sel] += Mb@Wd.
// GEMM: M=128, 128x32 tile, BK=64, 4 waves (2x2), 16x16x32 bf16 MFMA,
// fp32 weights cvt_pk'd to bf16 during LDS staging, register prefetch,
// split-K fp32 atomics. Grids sized for >=2 blocks/CU (latency hiding via
// occupancy was the round-2 bottleneck: 1 block/CU -> 1.16 TB/s).

#define D_ 2048
#define I_ 5504
#define NROWS 256
#define KSEL 128

typedef __attribute__((ext_vector_type(8))) short short8;   // 8 x bf16
typedef __attribute__((ext_vector_type(4))) float floatx4;  // MFMA acc

__device__ __forceinline__ unsigned short f2bf(float f) {
  union { float f; unsigned int u; } v; v.f = f;
  unsigned int r = (v.u + 0x7FFFu + ((v.u >> 16) & 1u)) >> 16;  // RNE
  return (unsigned short)r;
}

__device__ __forceinline__ unsigned int pk2(float lo, float hi) {
  __hip_bfloat162 h = __float22bfloat162_rn(float2{lo, hi});  // v_cvt_pk_bf16_f32
  unsigned int u; __builtin_memcpy(&u, &h, 4); return u;
}

// ---------------- K1: router scores ----------------
__global__ void k_router(const float* __restrict__ hid, const float* __restrict__ rw,
                         const float* __restrict__ rb, float* __restrict__ scores) {
  int b = blockIdx.x, t = threadIdx.x;
  const float* x = hid + (size_t)b * D_;
  float s = 0.f;
  for (int i = t; i < D_; i += 256) s += x[i] * rw[i];
  for (int o = 32; o; o >>= 1) s += __shfl_down(s, o);
  __shared__ float red[4];
  if ((t & 63) == 0) red[t >> 6] = s;
  __syncthreads();
  if (t == 0) scores[b] = red[0] + red[1] + red[2] + red[3] + rb[0];
}

// ---------------- K2: exact top-k, deterministic (rank == slot) ----------------
__global__ void k_select(const float* __restrict__ scores, const int* __restrict__ kptr,
                         int* __restrict__ sel, int* __restrict__ pos) {
  __shared__ float sv[NROWS];
  int t = threadIdx.x;
  sv[t] = scores[t];
  __syncthreads();
  float s = sv[t];
  int c = 0;
  for (int j = 0; j < NROWS; ++j) {
    float o = sv[j];
    c += (o > s) || (o == s && j < t);
  }
  int k = *kptr;                 // k_sel == 128 (grids sized for it)
  if (c < k) sel[c] = t;
  pos[t] = (c < k) ? c : -1;
}

// ---------------- K3: rms1, init V=bv, X1=x, H bf16 ----------------
__global__ void k_rms1(const float* __restrict__ hid, const int* __restrict__ sel,
                       const float* __restrict__ ln1, const float* __restrict__ bv,
                       unsigned short* __restrict__ Hb, float* __restrict__ V,
                       float* __restrict__ X1) {
  int i = blockIdx.x, t = threadIdx.x;
  int r = sel[i];
  const float* x = hid + (size_t)r * D_;
  float xs[8]; float ss = 0.f;
#pragma unroll
  for (int c = 0; c < 8; ++c) { float v = x[t + c * 256]; xs[c] = v; ss += v * v; }
  for (int o = 32; o; o >>= 1) ss += __shfl_down(ss, o);
  __shared__ float red[4];
  if ((t & 63) == 0) red[t >> 6] = ss;
  __syncthreads();
  float inv = rsqrtf((red[0] + red[1] + red[2] + red[3]) * (1.0f / D_) + 1e-6f);
#pragma unroll
  for (int c = 0; c < 8; ++c) {
    int idx = t + c * 256;
    size_t o_ = (size_t)i * D_ + idx;
    Hb[o_] = f2bf(xs[c] * inv * ln1[idx]);
    V[o_] = bv[idx];
    X1[o_] = xs[c];
  }
}

// ---------------- K5: rms2, zero G/U ----------------
__global__ void k_rms2(const float* __restrict__ X1, const float* __restrict__ ln2,
                       unsigned short* __restrict__ H2b, float* __restrict__ G,
                       float* __restrict__ U) {
  int i = blockIdx.x, t = threadIdx.x;
  const float* x = X1 + (size_t)i * D_;
  float xs[8]; float ss = 0.f;
#pragma unroll
  for (int c = 0; c < 8; ++c) { float v = x[t + c * 256]; xs[c] = v; ss += v * v; }
  for (int o = 32; o; o >>= 1) ss += __shfl_down(ss, o);
  __shared__ float red[4];
  if ((t & 63) == 0) red[t >> 6] = ss;
  __syncthreads();
  float inv = rsqrtf((red[0] + red[1] + red[2] + red[3]) * (1.0f / D_) + 1e-6f);
#pragma unroll
  for (int c = 0; c < 8; ++c) {
    int idx = t + c * 256;
    H2b[(size_t)i * D_ + idx] = f2bf(xs[c] * inv * ln2[idx]);
  }
  for (int j = t; j < I_; j += 256) {
    G[(size_t)i * I_ + j] = 0.f;
    U[(size_t)i * I_ + j] = 0.f;
  }
}

// ---------------- K7: Mb = silu(G)*U ; out = copy/scatter ----------------
__global__ void k_silu_out(const float* __restrict__ G, const float* __restrict__ U,
                           unsigned short* __restrict__ Mb,
                           const float* __restrict__ X1, const int* __restrict__ pos,
                           const float* __restrict__ hid, float* __restrict__ out) {
  int tid = blockIdx.x * 256 + threadIdx.x;
  int stride = gridDim.x * 256;
  const int nM = KSEL * I_;    // 704512
  for (int i = tid; i < nM; i += stride) {
    float g = G[i], u = U[i];
    float m = (g / (1.f + expf(-g))) * u;
    Mb[i] = f2bf(m);
  }
  const int nO4 = NROWS * (D_ / 4);   // 131072 float4
  const float4* X14 = (const float4*)X1;
  const float4* H4 = (const float4*)hid;
  float4* O4 = (float4*)out;
  for (int i = tid; i < nO4; i += stride) {
    int row = i >> 9;             // 512 float4 per row
    int c4 = i & 511;
    int p = pos[row];
    O4[i] = (p >= 0) ? X14[(size_t)p * 512 + c4] : H4[i];
  }
}

// ---------------- GEMM: C[128xN] += A[128xKA] @ B[KbxN] ----------------
// 128x32 tile, BK=64, 4 waves (2 wm x 2 wn), 16x16x32 bf16 MFMA.
// K = iteration space (KT*gridDim.y, may exceed KA for tail padding);
// A chunks with col>=KA are zero-filled, B rows clamped to Kb-1 (harmless:
// multiplied by zero A). Register prefetch of next tile during MFMA phase.
template<bool AF32, bool DUAL>
__global__ __launch_bounds__(256, 2)
void k_gemm(const void* __restrict__ Ap, const float* __restrict__ B0,
            const float* __restrict__ B1, float* __restrict__ C0,
            float* __restrict__ C1, const int* __restrict__ rowmap,
            int K, int KA, int Kb, int lda, int N, int KT, int ldc) {
  constexpr int ST = 72;   // LDS stride (elems): 144 B rows, b128-aligned, 2-way max
  const int bn = blockIdx.x;
  const int kt0 = blockIdx.y * KT;
  const int kt1 = kt0 + KT;
  const int tid = threadIdx.x;
  const int lane = tid & 63;
  const int wave = tid >> 6;
  const int wm = wave >> 1, wn = wave & 1;
  const int fm = lane & 15, kq = lane >> 4;

  __shared__ alignas(16) unsigned short Asm[128 * ST];            // 18 KB
  __shared__ alignas(16) unsigned short Bsm0[32 * ST];            // 4.5 KB
  __shared__ alignas(16) unsigned short Bsm1[DUAL ? 32 * ST : 8];

  floatx4 acc0[4] = {};
  floatx4 acc1[4] = {};

  // A staging: thread -> (row ar, 32-col half ah)
  const int ar = tid >> 1;
  const int ah = (tid & 1) * 32;
  // B staging: thread -> (col bnn, 8-row group bk8); one ds_write_b128 per B
  const int bnn = tid & 31;
  const int bk8 = (tid >> 5) * 8;

  const unsigned short* Ab = AF32 ? nullptr : (const unsigned short*)Ap + (size_t)ar * lda + ah;
  const float*          Af = AF32 ? (const float*)Ap + (size_t)ar * lda + ah : nullptr;
  const float* B0c = B0 + (size_t)(bn * 32 + bnn);
  const float* B1c = DUAL ? B1 + (size_t)(bn * 32 + bnn) : nullptr;

  // prefetch registers
  uint4 a4[4];        // bf16 A: 32 cols
  float4 af8[8];      // fp32 A: 32 cols
  float b0v[8], b1v[8];

  auto load_tile = [&](int kt) {
    if (AF32) {
#pragma unroll
      for (int r = 0; r < 8; ++r) {
        int c0 = kt + ah + r * 4;
        af8[r] = (c0 < KA) ? *(const float4*)(Af + kt + r * 4)
                           : make_float4(0.f, 0.f, 0.f, 0.f);
      }
    } else {
#pragma unroll
      for (int r = 0; r < 4; ++r) {
        int c0 = kt + ah + r * 8;
        a4[r] = (c0 < KA) ? *(const uint4*)(Ab + kt + r * 8)
                          : make_uint4(0u, 0u, 0u, 0u);
      }
    }
#pragma unroll
    for (int j = 0; j < 8; ++j) {
      int kr = kt + bk8 + j; kr = kr < Kb ? kr : Kb - 1;
      b0v[j] = B0c[(size_t)kr * N];
      if (DUAL) b1v[j] = B1c[(size_t)kr * N];
    }
  };

  load_tile(kt0);

  for (int kt = kt0; kt < kt1; kt += 64) {
    __syncthreads();   // previous iteration's LDS readers done
    // ---- store staged tile to LDS ----
    {
      uint4* Ad = (uint4*)&Asm[ar * ST + ah];
      if (AF32) {
        uint4 q;
#pragma unroll
        for (int r = 0; r < 4; ++r) {
          q.x = pk2(af8[2 * r].x, af8[2 * r].y);
          q.y = pk2(af8[2 * r].z, af8[2 * r].w);
          q.z = pk2(af8[2 * r + 1].x, af8[2 * r + 1].y);
          q.w = pk2(af8[2 * r + 1].z, af8[2 * r + 1].w);
          Ad[r] = q;
        }
      } else {
#pragma unroll
        for (int r = 0; r < 4; ++r) Ad[r] = a4[r];
      }
      uint4 bq;
      bq.x = pk2(b0v[0], b0v[1]); bq.y = pk2(b0v[2], b0v[3]);
      bq.z = pk2(b0v[4], b0v[5]); bq.w = pk2(b0v[6], b0v[7]);
      *(uint4*)&Bsm0[bnn * ST + bk8] = bq;
      if (DUAL) {
        uint4 cq;
        cq.x = pk2(b1v[0], b1v[1]); cq.y = pk2(b1v[2], b1v[3]);
        cq.z = pk2(b1v[4], b1v[5]); cq.w = pk2(b1v[6], b1v[7]);
        *(uint4*)&Bsm1[bnn * ST + bk8] = cq;
      }
    }
    __syncthreads();   // tile visible
    // ---- prefetch next tile (hides behind MFMA below) ----
    if (kt + 64 < kt1) load_tile(kt + 64);
    // ---- fragments + MFMA (2 K-steps of 32) ----
    short8 afr[2][4], bf0[2], bf1[2];
#pragma unroll
    for (int s = 0; s < 2; ++s) {
#pragma unroll
      for (int i = 0; i < 4; ++i)
        afr[s][i] = *(const short8*)&Asm[(wm * 64 + i * 16 + fm) * ST + s * 32 + kq * 8];
      bf0[s] = *(const short8*)&Bsm0[(wn * 16 + fm) * ST + s * 32 + kq * 8];
      if (DUAL)
        bf1[s] = *(const short8*)&Bsm1[(wn * 16 + fm) * ST + s * 32 + kq * 8];
    }
#pragma unroll
    for (int s = 0; s < 2; ++s) {
#pragma unroll
      for (int i = 0; i < 4; ++i) {
        acc0[i] = __builtin_amdgcn_mfma_f32_16x16x32_bf16(afr[s][i], bf0[s], acc0[i], 0, 0, 0);
        if (DUAL)
          acc1[i] = __builtin_amdgcn_mfma_f32_16x16x32_bf16(afr[s][i], bf1[s], acc1[i], 0, 0, 0);
      }
    }
  }

  // epilogue: atomic accumulate (C/D layout: col=lane&15, row=(lane>>4)*4+reg)
#pragma unroll
  for (int i = 0; i < 4; ++i) {
#pragma unroll
    for (int r = 0; r < 4; ++r) {
      int row = wm * 64 + i * 16 + kq * 4 + r;
      size_t rbase = rowmap ? (size_t)rowmap[row] * ldc : (size_t)row * ldc;
      int col = bn * 32 + wn * 16 + fm;
      atomicAdd(&C0[rbase + col], acc0[i][r]);
      if (DUAL) atomicAdd(&C1[rbase + col], acc1[i][r]);
    }
  }
}

extern "C" void kernel_launch(void* const* d_in, const int* in_sizes, int n_in,
                              void* d_out, int out_size, void* d_ws, size_t ws_size,
                              hipStream_t stream) {
  const float* hid = (const float*)d_in[0];
  const float* rw  = (const float*)d_in[3];
  const float* rb  = (const float*)d_in[4];
  const float* ln1 = (const float*)d_in[5];
  const float* ln2 = (const float*)d_in[6];
  const float* wv  = (const float*)d_in[11];
  const float* bv  = (const float*)d_in[12];
  const float* wo  = (const float*)d_in[13];
  const float* wg  = (const float*)d_in[14];
  const float* wu  = (const float*)d_in[15];
  const float* wd  = (const float*)d_in[16];
  const int*   kp  = (const int*)d_in[17];
  float* out = (float*)d_out;

  char* ws = (char*)d_ws;
  float*          scores = (float*)(ws + 0);           // 1 KB
  int*            sel    = (int*)(ws + 1024);          // 512 B
  int*            pos    = (int*)(ws + 1536);          // 1 KB
  unsigned short* Hb     = (unsigned short*)(ws + 4096);        // 512 KB
  float*          V      = (float*)(ws + 528384);      // 1 MB
  float*          X1     = (float*)(ws + 1576960);     // 1 MB
  unsigned short* H2b    = (unsigned short*)(ws + 2625536);     // 512 KB
  float*          G      = (float*)(ws + 3149824);     // 2.69 MB
  float*          U      = (float*)(ws + 5967872);     // 2.69 MB
  unsigned short* Mb     = (unsigned short*)(ws + 8785920);     // 1.34 MB

  k_router<<<256, 256, 0, stream>>>(hid, rw, rb, scores);
  k_select<<<1, 256, 0, stream>>>(scores, kp, sel, pos);
  k_rms1<<<128, 256, 0, stream>>>(hid, sel, ln1, bv, Hb, V, X1);
  // V += Hb @ wv   (64 n-tiles x 8 splits = 512 blocks ~ 2/CU, 4 iters)
  k_gemm<false, false><<<dim3(64, 8), 256, 0, stream>>>(
      Hb, wv, nullptr, V, nullptr, nullptr, 2048, 2048, 2048, 2048, 2048, 256, 2048);
  // X1 += V @ wo  (A fp32)
  k_gemm<true, false><<<dim3(64, 8), 256, 0, stream>>>(
      V, wo, nullptr, X1, nullptr, nullptr, 2048, 2048, 2048, 2048, 2048, 256, 2048);
  k_rms2<<<128, 256, 0, stream>>>(X1, ln2, H2b, G, U);
  // G,U += H2b @ {wg,wu}  (172 n-tiles x 4 splits = 688 blocks ~ 2.7/CU, 8 iters)
  k_gemm<false, true><<<dim3(172, 4), 256, 0, stream>>>(
      H2b, wg, wu, G, U, nullptr, 2048, 2048, 2048, 2048, 5504, 512, 5504);
  k_silu_out<<<1024, 256, 0, stream>>>(G, U, Mb, X1, pos, hid, out);
  // out[sel] += Mb @ wd  (64 x 8 = 512 blocks, KT=704 -> K=5632 padded, 11 iters)
  k_gemm<false, false><<<dim3(64, 8), 256, 0, stream>>>(
      Mb, wd, nullptr, out, nullptr, sel, 5632, 5504, 5504, 5504, 2048, 704, 2048);
}